// Round 11
// baseline (4621.817 us; speedup 1.0000x reference)
//
#include <hip/hip_runtime.h>
#include <hip/hip_cooperative_groups.h>

namespace cg = cooperative_groups;

#define Dd 1024
#define Bb 128
#define Tt 256
#define NWG 128
#define NTHR 512

typedef short bf16x8 __attribute__((ext_vector_type(8)));
typedef float f32x4 __attribute__((ext_vector_type(4)));
typedef unsigned int u32x4 __attribute__((ext_vector_type(4)));
typedef unsigned long long u64;

static __device__ __forceinline__ unsigned short f2bf(float x) {
  unsigned int u = __float_as_uint(x);
  u += 0x7fffu + ((u >> 16) & 1u);   // round-to-nearest-even
  return (unsigned short)(u >> 16);
}
static __device__ __forceinline__ unsigned int pk2(float a, float b) {
  return (unsigned int)f2bf(a) | ((unsigned int)f2bf(b) << 16);
}
static __device__ __forceinline__ bf16x8 as_bf(uint4 u) {
  union { uint4 u; bf16x8 v; } x; x.u = u; return x.v;
}
static __device__ __forceinline__ f32x4 mfma_(bf16x8 a, bf16x8 b, f32x4 c) {
  return __builtin_amdgcn_mfma_f32_16x16x32_bf16(a, b, c, 0, 0, 0);
}
static __device__ __forceinline__ float sigm(float x) { return 1.f / (1.f + __expf(-x)); }
static __device__ __forceinline__ float tanh_s(float x) { return 1.f - 2.f / (__expf(2.f * x) + 1.f); }
static __device__ __forceinline__ u64 aload(const u64* p) {
  return __hip_atomic_load(p, __ATOMIC_RELAXED, __HIP_MEMORY_SCOPE_AGENT);
}

// 128 WGs x 512 thr (8 waves). WG = hidden-slice gs of 8 dims, FULL batch
// (wave w handles batch rows [16w,16w+16)). 2 waves/SIMD -> real TLP.
// LDS: W_ih+W_hh slices packed as MFMA B-fragments (128 KB, resident).
// h ring: 257 slots of 256KB; producers write-through (sc0 sc1), consumers
// use NORMAL cached loads (single-writer slots, read-after-flag). RING=0
// fallback uses coherent-point atomic loads on a 2-slot buffer.
// Flags: per-wave monotone ints flags[gs][wave 0..7], plain agent stores;
// wave0 polls all 1024 (2 u64/lane), relays via LDS sentinel.
// Loop order (deferred-ack): wait(t) -> h-GEMM(t) -> pointwise -> transpose
// -> store h(t+1) -> x-GEMM(t+1) -> vmcnt(0) -> flag(t+1).
template<int RING>
__global__ void __launch_bounds__(NTHR, 1) lstm_kernel(
    const float* __restrict__ inp, const float* __restrict__ h0,
    const float* __restrict__ c0, const float* __restrict__ W_ih,
    const float* __restrict__ W_hh, const float* __restrict__ b_ih,
    const float* __restrict__ b_hh, const float* __restrict__ fc_w,
    const float* __restrict__ fc_b, float* __restrict__ out,
    int* __restrict__ flags, unsigned short* __restrict__ hbuf,
    unsigned short* __restrict__ xbf, int use_xbf)
{
  extern __shared__ uint4 ldsW[];   // 8192 fragments = 128 KB
  __shared__ float red[8];
  __shared__ int sent;

  const int tid = threadIdx.x;
  const int wg  = blockIdx.x;
  const int gid = wg * NTHR + tid;
  cg::grid_group grid = cg::this_grid();

  const int gs = wg;                // hidden slice 0..127

  // ---------- flag init: 8 per WG (one per wave), layout [gs][wave]
  if (tid < 8)
    __hip_atomic_store(&flags[gs * 8 + tid], 0,
                       __ATOMIC_RELAXED, __HIP_MEMORY_SCOPE_AGENT);
  if (tid == 0) sent = -1;

  // ---------- Phase A: inp [B,T,D] f32 -> xbf [T,B,D] bf16 ; h0 -> slot 0
  if (use_xbf) {
    for (int i = gid; i < Tt * Bb * (Dd / 8); i += NWG * NTHR) {
      int d8 = i & 127, b = (i >> 7) & 127, t = i >> 14;
      const float* s = inp + ((size_t)b * Tt + t) * Dd + d8 * 8;
      uint4 p;
      p.x = pk2(s[0], s[1]); p.y = pk2(s[2], s[3]);
      p.z = pk2(s[4], s[5]); p.w = pk2(s[6], s[7]);
      *(uint4*)(xbf + (size_t)i * 8) = p;
    }
  }
  // h0 [b][d] f32 -> slot0 [d>>3][b][d&7] bf16
  uint4* hb4w = (uint4*)hbuf;
  for (int i = gid; i < 128 * 128; i += NWG * NTHR) {
    int row = i & 127, gsl = i >> 7;
    const float* s = h0 + (size_t)row * Dd + gsl * 8;
    uint4 p;
    p.x = pk2(s[0], s[1]); p.y = pk2(s[2], s[3]);
    p.z = pk2(s[4], s[5]); p.w = pk2(s[6], s[7]);
    hb4w[gsl * 128 + row] = p;
  }

  // ---------- Phase B: pack W slices into LDS (bf16, fragment order)
  for (int i = tid; i < 8192; i += NTHR) {
    int l2 = i & 63, mmct = (i >> 6) & 3, kc = i >> 8;
    int cc = l2 & 15, ct = mmct & 1;
    int row = (((ct << 1) | (cc >> 3)) << 10) | (gs << 3) | (cc & 7);
    int k = kc * 32 + ((l2 >> 4) << 3);
    const float* s = ((mmct & 2) ? W_hh : W_ih) + (size_t)row * Dd + k;
    uint4 p;
    p.x = pk2(s[0], s[1]); p.y = pk2(s[2], s[3]);
    p.z = pk2(s[4], s[5]); p.w = pk2(s[6], s[7]);
    ldsW[i] = p;
  }

  // ---------- per-thread setup
  const int w = tid >> 6, l = tid & 63;   // wave 0..7
  const int c = l & 15;
  const int rowbase = w * 16;             // full batch across 8 waves
  const int arow = rowbase + c;           // A-fragment batch row
  const int koff8 = l >> 4;               // k sub-chunk (0..3) within 32
  const int r0 = ((c >> 3) << 10) | (gs << 3) | (c & 7);        // i/f row
  const int r1 = ((2 + (c >> 3)) << 10) | (gs << 3) | (c & 7);  // g/o row
  const float bias0 = b_ih[r0] + b_hh[r0];
  const float bias1 = b_ih[r1] + b_hh[r1];
  const int dim = (gs << 3) | (c & 7);
  const int crow = rowbase + (koff8 << 2);      // C/D fragment row base
  float creg[4];
  #pragma unroll
  for (int j = 0; j < 4; ++j) creg[j] = c0[(size_t)(crow + j) * Dd + dim];

  float* out_y = out;
  float* out_h = out + Bb;
  float* out_c = out + Bb + (size_t)Bb * Dd;

  int* myflag = &flags[gs * 8 + w];
  const u64* fq = (const u64*)flags;            // 512 u64 = all 1024 flags
  const int shbase = ((l & 15) >> 2) * 16;      // shfl source base

  grid.sync();   // one-time: publish flag init, xbf, slot0 (release+acquire)

  // ---------- x-GEMM accumulators carried across iterations
  f32x4 pa0, pa1, pb0, pb1;

  // prologue: x-part for t = 0
  {
    pa0 = f32x4{bias0, bias0, bias0, bias0};
    pa1 = f32x4{bias1, bias1, bias1, bias1};
    pb0 = f32x4{0.f, 0.f, 0.f, 0.f};
    pb1 = f32x4{0.f, 0.f, 0.f, 0.f};
    if (use_xbf) {
      const uint4* xA = (const uint4*)(xbf + ((size_t)0 * Bb + arow) * Dd + koff8 * 8);
      #pragma unroll
      for (int kc = 0; kc < 32; kc += 2) {
        uint4 ax0 = xA[kc * 4];
        uint4 ax1 = xA[(kc + 1) * 4];
        const int lb0 = kc * 256 + l, lb1 = (kc + 1) * 256 + l;
        pa0 = mfma_(as_bf(ax0), as_bf(ldsW[lb0]),      pa0);
        pa1 = mfma_(as_bf(ax0), as_bf(ldsW[lb0 + 64]), pa1);
        pb0 = mfma_(as_bf(ax1), as_bf(ldsW[lb1]),      pb0);
        pb1 = mfma_(as_bf(ax1), as_bf(ldsW[lb1 + 64]), pb1);
      }
    } else {
      const float* xF = inp + ((size_t)arow * Tt + 0) * Dd + koff8 * 8;
      #pragma unroll 4
      for (int kc = 0; kc < 32; ++kc) {
        const float* xs = xF + kc * 32;
        uint4 axu;
        axu.x = pk2(xs[0], xs[1]); axu.y = pk2(xs[2], xs[3]);
        axu.z = pk2(xs[4], xs[5]); axu.w = pk2(xs[6], xs[7]);
        const int lb = kc * 256 + l;
        pa0 = mfma_(as_bf(axu), as_bf(ldsW[lb]),      pa0);
        pa1 = mfma_(as_bf(axu), as_bf(ldsW[lb + 64]), pa1);
      }
    }
  }

  // ---------- sequential scan (no syncthreads, no fences)
  for (int t = 0; t < Tt; ++t) {
    const int rslot = RING ? t : (t & 1);
    const int wslot = RING ? (t + 1) : ((t + 1) & 1);

    // ---- wait for h(t): wave 0 polls all 1024 flags, others spin sentinel
    if (w == 0) {
      int ok;
      do {
        u64 a = aload(&fq[l]);
        u64 b = aload(&fq[l + 64]);
        ok = ((int)a >= t) && ((int)(a >> 32) >= t) &&
             ((int)b >= t) && ((int)(b >> 32) >= t);
      } while (!__all(ok));
      __hip_atomic_store(&sent, t, __ATOMIC_RELEASE, __HIP_MEMORY_SCOPE_WORKGROUP);
    } else {
      while (__hip_atomic_load(&sent, __ATOMIC_ACQUIRE, __HIP_MEMORY_SCOPE_WORKGROUP) < t) {}
    }
    asm volatile("" ::: "memory");   // compiler fence: no h-load hoisting

    // ---- h-part
    if constexpr (RING) {
      const uint4* hA4 = (const uint4*)(hbuf + (size_t)rslot * 131072);
      #pragma unroll
      for (int kc = 0; kc < 32; kc += 2) {
        uint4 h0u = hA4[(kc * 4 + koff8) * 128 + arow];
        uint4 h1u = hA4[((kc + 1) * 4 + koff8) * 128 + arow];
        const int lb0 = kc * 256 + l, lb1 = (kc + 1) * 256 + l;
        pa0 = mfma_(as_bf(h0u), as_bf(ldsW[lb0 + 128]), pa0);
        pa1 = mfma_(as_bf(h0u), as_bf(ldsW[lb0 + 192]), pa1);
        pb0 = mfma_(as_bf(h1u), as_bf(ldsW[lb1 + 128]), pb0);
        pb1 = mfma_(as_bf(h1u), as_bf(ldsW[lb1 + 192]), pb1);
      }
    } else {
      const u64* hA = (const u64*)hbuf + (size_t)rslot * 32768;
      #pragma unroll
      for (int kc = 0; kc < 32; kc += 2) {
        const int hi0 = (kc * 4 + koff8) * 256 + arow * 2;
        const int hi1 = ((kc + 1) * 4 + koff8) * 256 + arow * 2;
        union { u64 q[2]; uint4 p4; } h0u, h1u;
        h0u.q[0] = aload(&hA[hi0]); h0u.q[1] = aload(&hA[hi0 + 1]);
        h1u.q[0] = aload(&hA[hi1]); h1u.q[1] = aload(&hA[hi1 + 1]);
        const int lb0 = kc * 256 + l, lb1 = (kc + 1) * 256 + l;
        pa0 = mfma_(as_bf(h0u.p4), as_bf(ldsW[lb0 + 128]), pa0);
        pa1 = mfma_(as_bf(h0u.p4), as_bf(ldsW[lb0 + 192]), pa1);
        pb0 = mfma_(as_bf(h1u.p4), as_bf(ldsW[lb1 + 128]), pb0);
        pb1 = mfma_(as_bf(h1u.p4), as_bf(ldsW[lb1 + 192]), pb1);
      }
    }
    f32x4 acc0 = pa0 + pb0;
    f32x4 acc1 = pa1 + pb1;

    // ---- pointwise (acc0: i|f, acc1: g|o split at col 8)
    float fo0[4], fo1[4];
    #pragma unroll
    for (int j = 0; j < 4; ++j) {
      fo0[j] = __shfl_xor(acc0[j], 8);
      fo1[j] = __shfl_xor(acc1[j], 8);
    }
    unsigned int bfu0 = 0, bfu1 = 0, bfu2 = 0, bfu3 = 0;
    if (c < 8) {
      float hnv[4];
      #pragma unroll
      for (int j = 0; j < 4; ++j) {
        float iv = sigm(acc0[j]);
        float fv = sigm(fo0[j]);
        float gv = tanh_s(acc1[j]);
        float ov = sigm(fo1[j]);
        float cn = fv * creg[j] + iv * gv;
        float hn2 = ov * tanh_s(cn);
        creg[j] = cn;
        hnv[j] = hn2;
        if (t == Tt - 1) {
          size_t off = (size_t)(crow + j) * Dd + dim;
          __hip_atomic_store(&out_h[off], hn2, __ATOMIC_RELAXED, __HIP_MEMORY_SCOPE_AGENT);
          __hip_atomic_store(&out_c[off], cn, __ATOMIC_RELAXED, __HIP_MEMORY_SCOPE_AGENT);
        }
      }
      bfu0 = f2bf(hnv[0]); bfu1 = f2bf(hnv[1]);
      bfu2 = f2bf(hnv[2]); bfu3 = f2bf(hnv[3]);
    }

    // ---- in-wave transpose: lane r<16 gathers row (rowbase+r), dims 0..7
    unsigned int w0 = 0, w1 = 0, w2 = 0, w3 = 0;
    #pragma unroll
    for (int j = 0; j < 4; ++j) {
      unsigned int src = (j == 0) ? bfu0 : (j == 1) ? bfu1 : (j == 2) ? bfu2 : bfu3;
      unsigned int lo0 = __shfl((int)src, shbase + 0);
      unsigned int hi0g = __shfl((int)src, shbase + 1);
      unsigned int lo1 = __shfl((int)src, shbase + 2);
      unsigned int hi1g = __shfl((int)src, shbase + 3);
      unsigned int lo2 = __shfl((int)src, shbase + 4);
      unsigned int hi2g = __shfl((int)src, shbase + 5);
      unsigned int lo3 = __shfl((int)src, shbase + 6);
      unsigned int hi3g = __shfl((int)src, shbase + 7);
      bool mine = ((l & 3) == j);
      if (mine) {
        w0 = lo0 | (hi0g << 16);
        w1 = lo1 | (hi1g << 16);
        w2 = lo2 | (hi2g << 16);
        w3 = lo3 | (hi3g << 16);
      }
    }
    // ---- publish h(t+1) (no ack wait yet)
    if (l < 16) {
      u32x4 val = {w0, w1, w2, w3};
      unsigned short* hw = hbuf + (size_t)wslot * 131072
                           + (size_t)gs * 1024 + (size_t)(rowbase + l) * 8;
      asm volatile("global_store_dwordx4 %0, %1, off sc0 sc1"
                   :: "v"(hw), "v"(val) : "memory");
    }

    // ---- x-part for step t+1 (hides the publish-ack round trip)
    pa0 = f32x4{bias0, bias0, bias0, bias0};
    pa1 = f32x4{bias1, bias1, bias1, bias1};
    pb0 = f32x4{0.f, 0.f, 0.f, 0.f};
    pb1 = f32x4{0.f, 0.f, 0.f, 0.f};
    if (t < Tt - 1) {
      if (use_xbf) {
        const uint4* xA = (const uint4*)(xbf + ((size_t)(t + 1) * Bb + arow) * Dd + koff8 * 8);
        #pragma unroll
        for (int kc = 0; kc < 32; kc += 2) {
          uint4 ax0 = xA[kc * 4];
          uint4 ax1 = xA[(kc + 1) * 4];
          const int lb0 = kc * 256 + l, lb1 = (kc + 1) * 256 + l;
          pa0 = mfma_(as_bf(ax0), as_bf(ldsW[lb0]),      pa0);
          pa1 = mfma_(as_bf(ax0), as_bf(ldsW[lb0 + 64]), pa1);
          pb0 = mfma_(as_bf(ax1), as_bf(ldsW[lb1]),      pb0);
          pb1 = mfma_(as_bf(ax1), as_bf(ldsW[lb1 + 64]), pb1);
        }
      } else {
        const float* xF = inp + ((size_t)arow * Tt + (t + 1)) * Dd + koff8 * 8;
        #pragma unroll 4
        for (int kc = 0; kc < 32; ++kc) {
          const float* xs = xF + kc * 32;
          uint4 axu;
          axu.x = pk2(xs[0], xs[1]); axu.y = pk2(xs[2], xs[3]);
          axu.z = pk2(xs[4], xs[5]); axu.w = pk2(xs[6], xs[7]);
          const int lb = kc * 256 + l;
          pa0 = mfma_(as_bf(axu), as_bf(ldsW[lb]),      pa0);
          pa1 = mfma_(as_bf(axu), as_bf(ldsW[lb + 64]), pa1);
        }
      }
    }

    // ---- now drain the publish store and raise the flag
    asm volatile("s_waitcnt vmcnt(0)" ::: "memory");  // h(t+1) globally visible
    if (l == 0)
      __hip_atomic_store(myflag, t + 1, __ATOMIC_RELAXED, __HIP_MEMORY_SCOPE_AGENT);
  }

  // ---------- fc head: yhat[b] = sigmoid(hx[b,:] . fc_w + fc_b)
  {
    // wait for ALL WGs to finish
    {
      int ok;
      do {
        u64 a = aload(&fq[l]);
        u64 b = aload(&fq[l + 64]);
        ok = ((int)a >= Tt) && ((int)(a >> 32) >= Tt) &&
             ((int)b >= Tt) && ((int)(b >> 32) >= Tt);
      } while (!__all(ok));
    }
    const u64* hr = (const u64*)(out_h + (size_t)wg * Dd);
    float s = 0.f;
    for (int k = tid; k < Dd / 2; k += NTHR) {
      u64 v = aload(&hr[k]);
      union { u64 u; float f[2]; } q; q.u = v;
      s += q.f[0] * fc_w[2 * k] + q.f[1] * fc_w[2 * k + 1];
    }
    #pragma unroll
    for (int off = 32; off > 0; off >>= 1) s += __shfl_down(s, off);
    if (l == 0) red[w] = s;
    __syncthreads();
    if (tid == 0) {
      float tot = fc_b[0];
      #pragma unroll
      for (int i = 0; i < 8; ++i) tot += red[i];
      out_y[wg] = sigm(tot);
    }
  }
}

extern "C" void kernel_launch(void* const* d_in, const int* in_sizes, int n_in,
                              void* d_out, int out_size, void* d_ws, size_t ws_size,
                              hipStream_t stream) {
  (void)in_sizes; (void)n_in; (void)out_size;
  const float* inp  = (const float*)d_in[0];
  const float* h0   = (const float*)d_in[1];
  const float* c0   = (const float*)d_in[2];
  const float* W_ih = (const float*)d_in[3];
  const float* W_hh = (const float*)d_in[4];
  const float* b_ih = (const float*)d_in[5];
  const float* b_hh = (const float*)d_in[6];
  const float* fc_w = (const float*)d_in[7];
  const float* fc_b = (const float*)d_in[8];
  float* out = (float*)d_out;

  const size_t fbytes = 16384;                         // flags (4 KB used)
  const size_t slot   = (size_t)Bb * Dd * 2;           // 256 KB
  const size_t ring1  = (size_t)(Tt + 1) * slot;       // 67.4 MB
  const size_t ring0  = 2 * slot;                      // 512 KB
  const size_t xbytes = (size_t)Tt * Bb * Dd * 2;      // 64 MB

  int ring, use_xbf;
  size_t rbytes;
  if (ws_size >= fbytes + ring1 + xbytes)      { ring = 1; use_xbf = 1; rbytes = ring1; }
  else if (ws_size >= fbytes + ring1)          { ring = 1; use_xbf = 0; rbytes = ring1; }
  else if (ws_size >= fbytes + ring0 + xbytes) { ring = 0; use_xbf = 1; rbytes = ring0; }
  else                                         { ring = 0; use_xbf = 0; rbytes = ring0; }

  int* flags = (int*)d_ws;
  unsigned short* hbuf = (unsigned short*)((char*)d_ws + fbytes);
  unsigned short* xbf  = (unsigned short*)((char*)d_ws + fbytes + rbytes);

  void* kfn = ring ? (void*)lstm_kernel<1> : (void*)lstm_kernel<0>;
  (void)hipFuncSetAttribute((const void*)kfn,
                            hipFuncAttributeMaxDynamicSharedMemorySize, 131072);

  void* kargs[] = {(void*)&inp, (void*)&h0, (void*)&c0, (void*)&W_ih, (void*)&W_hh,
                   (void*)&b_ih, (void*)&b_hh, (void*)&fc_w, (void*)&fc_b,
                   (void*)&out, (void*)&flags, (void*)&hbuf, (void*)&xbf, (void*)&use_xbf};
  (void)hipLaunchCooperativeKernel(kfn, dim3(NWG), dim3(NTHR),
                                   kargs, 131072u, stream);
}

// Round 12
// 4212.612 us; speedup vs baseline: 1.0971x; 1.0971x over previous
//
#include <hip/hip_runtime.h>
#include <hip/hip_cooperative_groups.h>

namespace cg = cooperative_groups;

#define Dd 1024
#define Bb 128
#define Tt 256
#define NWG 256
#define NTHR 256

typedef short bf16x8 __attribute__((ext_vector_type(8)));
typedef float f32x4 __attribute__((ext_vector_type(4)));
typedef unsigned int u32x4 __attribute__((ext_vector_type(4)));
typedef unsigned long long u64;

static __device__ __forceinline__ unsigned short f2bf(float x) {
  unsigned int u = __float_as_uint(x);
  u += 0x7fffu + ((u >> 16) & 1u);   // round-to-nearest-even
  return (unsigned short)(u >> 16);
}
static __device__ __forceinline__ unsigned int pk2(float a, float b) {
  return (unsigned int)f2bf(a) | ((unsigned int)f2bf(b) << 16);
}
static __device__ __forceinline__ float bf2f(unsigned int ubits) {
  return __uint_as_float(ubits << 16);
}
static __device__ __forceinline__ bf16x8 as_bf(uint4 u) {
  union { uint4 u; bf16x8 v; } x; x.u = u; return x.v;
}
static __device__ __forceinline__ f32x4 mfma_(bf16x8 a, bf16x8 b, f32x4 c) {
  return __builtin_amdgcn_mfma_f32_16x16x32_bf16(a, b, c, 0, 0, 0);
}
static __device__ __forceinline__ float sigm(float x) { return 1.f / (1.f + __expf(-x)); }
static __device__ __forceinline__ float tanh_s(float x) { return 1.f - 2.f / (__expf(2.f * x) + 1.f); }
static __device__ __forceinline__ u64 aload(const u64* p) {
  return __hip_atomic_load(p, __ATOMIC_RELAXED, __HIP_MEMORY_SCOPE_AGENT);
}

// ============================ TIER X KERNELS =============================
// Kernel 0: inp [B,T,D] f32 -> xbf [T,B,D] bf16
__global__ void xcvt_kernel(const float* __restrict__ inp,
                            unsigned short* __restrict__ xbf)
{
  for (int i = blockIdx.x * 256 + threadIdx.x; i < Tt * Bb * (Dd / 8);
       i += gridDim.x * 256) {
    int d8 = i & 127, b = (i >> 7) & 127, t = i >> 14;
    const float* s = inp + ((size_t)b * Tt + t) * Dd + d8 * 8;
    uint4 p;
    p.x = pk2(s[0], s[1]); p.y = pk2(s[2], s[3]);
    p.z = pk2(s[4], s[5]); p.w = pk2(s[6], s[7]);
    *(uint4*)(xbf + (size_t)i * 8) = p;
  }
}

// Kernel 1: xg[t][gate 0..4095][batch 0..127] bf16 = x_t . W_ih^T + b_ih + b_hh
// 256 WGs = (gs 0..127, bh 0..1); W_ih slice (32 gate rows) resident in LDS
// as MFMA B-fragments (64 KB). No barriers; fully latency-tolerant.
__global__ void __launch_bounds__(256, 1) xg_kernel(
    const unsigned short* __restrict__ xbf, const float* __restrict__ W_ih,
    const float* __restrict__ b_ih, const float* __restrict__ b_hh,
    unsigned short* __restrict__ xg)
{
  extern __shared__ uint4 ldsW[];   // 4096 fragments = 64 KB
  const int tid = threadIdx.x;
  const int wg  = blockIdx.x;
  const int gs = wg >> 1;
  const int bh = wg & 1;

  // pack W_ih slice: i = kc*128 + ct*64 + lane
  for (int i = tid; i < 4096; i += 256) {
    int l2 = i & 63, ct = (i >> 6) & 1, kc = i >> 7;
    int cc = l2 & 15;
    int row = (((ct << 1) | (cc >> 3)) << 10) | (gs << 3) | (cc & 7);
    int k = kc * 32 + ((l2 >> 4) << 3);
    const float* s = W_ih + (size_t)row * Dd + k;
    uint4 p;
    p.x = pk2(s[0], s[1]); p.y = pk2(s[2], s[3]);
    p.z = pk2(s[4], s[5]); p.w = pk2(s[6], s[7]);
    ldsW[i] = p;
  }
  __syncthreads();

  const int w = tid >> 6, l = tid & 63;
  const int c = l & 15;
  const int rowbase = bh * 64 + w * 16;
  const int arow = rowbase + c;
  const int koff8 = l >> 4;
  const int r0 = ((c >> 3) << 10) | (gs << 3) | (c & 7);
  const int r1 = ((2 + (c >> 3)) << 10) | (gs << 3) | (c & 7);
  const float bias0 = b_ih[r0] + b_hh[r0];
  const float bias1 = b_ih[r1] + b_hh[r1];
  const int crow = rowbase + (koff8 << 2);

  for (int t = 0; t < Tt; ++t) {
    f32x4 a0 = {bias0, bias0, bias0, bias0};
    f32x4 a1 = {bias1, bias1, bias1, bias1};
    f32x4 e0 = {0.f, 0.f, 0.f, 0.f};
    f32x4 e1 = {0.f, 0.f, 0.f, 0.f};
    const uint4* xA = (const uint4*)(xbf + ((size_t)t * Bb + arow) * Dd + koff8 * 8);
    #pragma unroll
    for (int kc = 0; kc < 32; kc += 2) {
      uint4 ax0 = xA[kc * 4];
      uint4 ax1 = xA[(kc + 1) * 4];
      const int lb0 = kc * 128 + l, lb1 = (kc + 1) * 128 + l;
      a0 = mfma_(as_bf(ax0), as_bf(ldsW[lb0]),      a0);
      a1 = mfma_(as_bf(ax0), as_bf(ldsW[lb0 + 64]), a1);
      e0 = mfma_(as_bf(ax1), as_bf(ldsW[lb1]),      e0);
      e1 = mfma_(as_bf(ax1), as_bf(ldsW[lb1 + 64]), e1);
    }
    f32x4 s0 = a0 + e0;
    f32x4 s1 = a1 + e1;
    u64 q0 = (u64)pk2(s0[0], s0[1]) | ((u64)pk2(s0[2], s0[3]) << 32);
    u64 q1 = (u64)pk2(s1[0], s1[1]) | ((u64)pk2(s1[2], s1[3]) << 32);
    *(u64*)(xg + (size_t)t * 524288 + (size_t)r0 * 128 + crow) = q0;
    *(u64*)(xg + (size_t)t * 524288 + (size_t)r1 * 128 + crow) = q1;
  }
}

// Kernel 2: the scan. 256 WGs x 256 thr = (gs, bh) as before, but only the
// h-GEMM remains in the loop (W_hh slice in 64 KB LDS); x-contribution comes
// from precomputed xg (2 u64 loads/thread, prefetched one step ahead).
// Ring + flags + barrier machinery identical to the proven R7/R10 structure.
__global__ void __launch_bounds__(256, 1) lstm_scan_kernel(
    const float* __restrict__ h0, const float* __restrict__ c0,
    const float* __restrict__ W_hh, const float* __restrict__ fc_w,
    const float* __restrict__ fc_b, float* __restrict__ out,
    int* __restrict__ flags, unsigned short* __restrict__ hbuf,
    const unsigned short* __restrict__ xg)
{
  extern __shared__ uint4 ldsW[];   // 4096 fragments = 64 KB
  __shared__ float red[4];
  __shared__ int sent;

  const int tid = threadIdx.x;
  const int wg  = blockIdx.x;
  const int gid = wg * 256 + tid;
  cg::grid_group grid = cg::this_grid();

  const int gs = wg >> 1;
  const int bh = wg & 1;

  if (tid < 4)
    __hip_atomic_store(&flags[bh * 512 + gs * 4 + tid], 0,
                       __ATOMIC_RELAXED, __HIP_MEMORY_SCOPE_AGENT);
  if (tid == 0) sent = -1;

  // h0 [b][d] f32 -> slot0 [d>>3][b][d&7] bf16
  uint4* hb4w = (uint4*)hbuf;
  for (int i = gid; i < 128 * 128; i += NWG * 256) {
    int row = i & 127, gsl = i >> 7;
    const float* s = h0 + (size_t)row * Dd + gsl * 8;
    uint4 p;
    p.x = pk2(s[0], s[1]); p.y = pk2(s[2], s[3]);
    p.z = pk2(s[4], s[5]); p.w = pk2(s[6], s[7]);
    hb4w[gsl * 128 + row] = p;
  }

  // pack W_hh slice
  for (int i = tid; i < 4096; i += 256) {
    int l2 = i & 63, ct = (i >> 6) & 1, kc = i >> 7;
    int cc = l2 & 15;
    int row = (((ct << 1) | (cc >> 3)) << 10) | (gs << 3) | (cc & 7);
    int k = kc * 32 + ((l2 >> 4) << 3);
    const float* s = W_hh + (size_t)row * Dd + k;
    uint4 p;
    p.x = pk2(s[0], s[1]); p.y = pk2(s[2], s[3]);
    p.z = pk2(s[4], s[5]); p.w = pk2(s[6], s[7]);
    ldsW[i] = p;
  }

  const int w = tid >> 6, l = tid & 63;
  const int c = l & 15;
  const int rowbase = bh * 64 + w * 16;
  const int arow = rowbase + c;
  const int koff8 = l >> 4;
  const int r0 = ((c >> 3) << 10) | (gs << 3) | (c & 7);
  const int r1 = ((2 + (c >> 3)) << 10) | (gs << 3) | (c & 7);
  const int dim = (gs << 3) | (c & 7);
  const int crow = rowbase + (koff8 << 2);
  float creg[4];
  #pragma unroll
  for (int j = 0; j < 4; ++j) creg[j] = c0[(size_t)(crow + j) * Dd + dim];

  float* out_y = out;
  float* out_h = out + Bb;
  float* out_c = out + Bb + (size_t)Bb * Dd;

  int* myflag = &flags[bh * 512 + gs * 4 + w];
  const u64* fq = (const u64*)(flags + bh * 512);
  const int shbase = ((l & 15) >> 2) * 16;

  grid.sync();   // one-time: publish flag init + slot0

  // prefetch xg(0)
  u64 xq0 = *(const u64*)(xg + (size_t)r0 * 128 + crow);
  u64 xq1 = *(const u64*)(xg + (size_t)r1 * 128 + crow);

  for (int t = 0; t < Tt; ++t) {
    // ---- wait for h(t)
    if (w == 0) {
      int ok;
      do {
        u64 a = aload(&fq[l]);
        u64 b = aload(&fq[l + 64]);
        u64 c2 = aload(&fq[l + 128]);
        u64 d2 = aload(&fq[l + 192]);
        ok = ((int)a >= t) && ((int)(a >> 32) >= t) &&
             ((int)b >= t) && ((int)(b >> 32) >= t) &&
             ((int)c2 >= t) && ((int)(c2 >> 32) >= t) &&
             ((int)d2 >= t) && ((int)(d2 >> 32) >= t);
      } while (!__all(ok));
      __hip_atomic_store(&sent, t, __ATOMIC_RELEASE, __HIP_MEMORY_SCOPE_WORKGROUP);
    } else {
      while (__hip_atomic_load(&sent, __ATOMIC_ACQUIRE, __HIP_MEMORY_SCOPE_WORKGROUP) < t) {}
    }
    asm volatile("" ::: "memory");

    // ---- h-GEMM (ring slot t, normal cached loads)
    f32x4 pa0 = {0.f, 0.f, 0.f, 0.f};
    f32x4 pa1 = {0.f, 0.f, 0.f, 0.f};
    f32x4 pb0 = {0.f, 0.f, 0.f, 0.f};
    f32x4 pb1 = {0.f, 0.f, 0.f, 0.f};
    {
      const uint4* hA4 = (const uint4*)(hbuf + (size_t)t * 131072);
      #pragma unroll
      for (int kc = 0; kc < 32; kc += 2) {
        uint4 h0u = hA4[(kc * 4 + koff8) * 128 + arow];
        uint4 h1u = hA4[((kc + 1) * 4 + koff8) * 128 + arow];
        const int lb0 = kc * 128 + l, lb1 = (kc + 1) * 128 + l;
        pa0 = mfma_(as_bf(h0u), as_bf(ldsW[lb0]),      pa0);
        pa1 = mfma_(as_bf(h0u), as_bf(ldsW[lb0 + 64]), pa1);
        pb0 = mfma_(as_bf(h1u), as_bf(ldsW[lb1]),      pb0);
        pb1 = mfma_(as_bf(h1u), as_bf(ldsW[lb1 + 64]), pb1);
      }
    }
    f32x4 acc0 = pa0 + pb0;
    f32x4 acc1 = pa1 + pb1;
    #pragma unroll
    for (int j = 0; j < 4; ++j) {
      acc0[j] += bf2f((unsigned int)(xq0 >> (16 * j)) & 0xffffu);
      acc1[j] += bf2f((unsigned int)(xq1 >> (16 * j)) & 0xffffu);
    }

    // ---- pointwise (acc0: i|f, acc1: g|o split at col 8)
    float fo0[4], fo1[4];
    #pragma unroll
    for (int j = 0; j < 4; ++j) {
      fo0[j] = __shfl_xor(acc0[j], 8);
      fo1[j] = __shfl_xor(acc1[j], 8);
    }
    unsigned int bfu0 = 0, bfu1 = 0, bfu2 = 0, bfu3 = 0;
    if (c < 8) {
      float hnv[4];
      #pragma unroll
      for (int j = 0; j < 4; ++j) {
        float iv = sigm(acc0[j]);
        float fv = sigm(fo0[j]);
        float gv = tanh_s(acc1[j]);
        float ov = sigm(fo1[j]);
        float cn = fv * creg[j] + iv * gv;
        float hn2 = ov * tanh_s(cn);
        creg[j] = cn;
        hnv[j] = hn2;
        if (t == Tt - 1) {
          size_t off = (size_t)(crow + j) * Dd + dim;
          __hip_atomic_store(&out_h[off], hn2, __ATOMIC_RELAXED, __HIP_MEMORY_SCOPE_AGENT);
          __hip_atomic_store(&out_c[off], cn, __ATOMIC_RELAXED, __HIP_MEMORY_SCOPE_AGENT);
        }
      }
      bfu0 = f2bf(hnv[0]); bfu1 = f2bf(hnv[1]);
      bfu2 = f2bf(hnv[2]); bfu3 = f2bf(hnv[3]);
    }

    // ---- in-wave transpose
    unsigned int w0 = 0, w1 = 0, w2 = 0, w3 = 0;
    #pragma unroll
    for (int j = 0; j < 4; ++j) {
      unsigned int src = (j == 0) ? bfu0 : (j == 1) ? bfu1 : (j == 2) ? bfu2 : bfu3;
      unsigned int lo0 = __shfl((int)src, shbase + 0);
      unsigned int hi0g = __shfl((int)src, shbase + 1);
      unsigned int lo1 = __shfl((int)src, shbase + 2);
      unsigned int hi1g = __shfl((int)src, shbase + 3);
      unsigned int lo2 = __shfl((int)src, shbase + 4);
      unsigned int hi2g = __shfl((int)src, shbase + 5);
      unsigned int lo3 = __shfl((int)src, shbase + 6);
      unsigned int hi3g = __shfl((int)src, shbase + 7);
      bool mine = ((l & 3) == j);
      if (mine) {
        w0 = lo0 | (hi0g << 16);
        w1 = lo1 | (hi1g << 16);
        w2 = lo2 | (hi2g << 16);
        w3 = lo3 | (hi3g << 16);
      }
    }
    // ---- publish h(t+1) (write-through), prefetch xg(t+1), drain, flag
    if (l < 16) {
      u32x4 val = {w0, w1, w2, w3};
      unsigned short* hw = hbuf + (size_t)(t + 1) * 131072
                           + (size_t)gs * 1024 + (size_t)(rowbase + l) * 8;
      asm volatile("global_store_dwordx4 %0, %1, off sc0 sc1"
                   :: "v"(hw), "v"(val) : "memory");
    }
    if (t + 1 < Tt) {
      xq0 = *(const u64*)(xg + (size_t)(t + 1) * 524288 + (size_t)r0 * 128 + crow);
      xq1 = *(const u64*)(xg + (size_t)(t + 1) * 524288 + (size_t)r1 * 128 + crow);
    }
    asm volatile("s_waitcnt vmcnt(0)" ::: "memory");
    if (l == 0)
      __hip_atomic_store(myflag, t + 1, __ATOMIC_RELAXED, __HIP_MEMORY_SCOPE_AGENT);
  }

  // ---------- fc head
  if (wg < Bb) {
    {
      const u64* fa = (const u64*)flags;
      int ok;
      do {
        ok = 1;
        #pragma unroll
        for (int r = 0; r < 8; ++r) {
          u64 v = aload(&fa[l + r * 64]);
          ok &= ((int)v >= Tt) && ((int)(v >> 32) >= Tt);
        }
      } while (!__all(ok));
    }
    const u64* hr = (const u64*)(out_h + (size_t)wg * Dd);
    float s = 0.f;
    for (int k = tid; k < Dd / 2; k += 256) {
      u64 v = aload(&hr[k]);
      union { u64 u; float f[2]; } q; q.u = v;
      s += q.f[0] * fc_w[2 * k] + q.f[1] * fc_w[2 * k + 1];
    }
    #pragma unroll
    for (int off = 32; off > 0; off >>= 1) s += __shfl_down(s, off);
    if (l == 0) red[w] = s;
    __syncthreads();
    if (tid == 0) {
      float tot = red[0] + red[1] + red[2] + red[3] + fc_b[0];
      out_y[wg] = sigm(tot);
    }
  }
}

// ===================== MONO FALLBACK (R10, verified 2914us) =====================
template<int RING>
__global__ void __launch_bounds__(NTHR, 1) lstm_kernel_mono(
    const float* __restrict__ inp, const float* __restrict__ h0,
    const float* __restrict__ c0, const float* __restrict__ W_ih,
    const float* __restrict__ W_hh, const float* __restrict__ b_ih,
    const float* __restrict__ b_hh, const float* __restrict__ fc_w,
    const float* __restrict__ fc_b, float* __restrict__ out,
    int* __restrict__ flags, unsigned short* __restrict__ hbuf,
    unsigned short* __restrict__ xbf, int use_xbf)
{
  extern __shared__ uint4 ldsW[];
  __shared__ float red[4];
  __shared__ int sent;

  const int tid = threadIdx.x;
  const int wg  = blockIdx.x;
  const int gid = wg * NTHR + tid;
  cg::grid_group grid = cg::this_grid();

  const int gs = wg >> 1;
  const int bh = wg & 1;

  if (tid < 4)
    __hip_atomic_store(&flags[bh * 512 + gs * 4 + tid], 0,
                       __ATOMIC_RELAXED, __HIP_MEMORY_SCOPE_AGENT);
  if (tid == 0) sent = -1;

  if (use_xbf) {
    for (int i = gid; i < Tt * Bb * (Dd / 8); i += NWG * NTHR) {
      int d8 = i & 127, b = (i >> 7) & 127, t = i >> 14;
      const float* s = inp + ((size_t)b * Tt + t) * Dd + d8 * 8;
      uint4 p;
      p.x = pk2(s[0], s[1]); p.y = pk2(s[2], s[3]);
      p.z = pk2(s[4], s[5]); p.w = pk2(s[6], s[7]);
      *(uint4*)(xbf + (size_t)i * 8) = p;
    }
  }
  uint4* hb4w = (uint4*)hbuf;
  for (int i = gid; i < 128 * 128; i += NWG * NTHR) {
    int row = i & 127, gsl = i >> 7;
    const float* s = h0 + (size_t)row * Dd + gsl * 8;
    uint4 p;
    p.x = pk2(s[0], s[1]); p.y = pk2(s[2], s[3]);
    p.z = pk2(s[4], s[5]); p.w = pk2(s[6], s[7]);
    hb4w[gsl * 128 + row] = p;
  }
  for (int i = tid; i < 8192; i += NTHR) {
    int l2 = i & 63, mmct = (i >> 6) & 3, kc = i >> 8;
    int cc = l2 & 15, ct = mmct & 1;
    int row = (((ct << 1) | (cc >> 3)) << 10) | (gs << 3) | (cc & 7);
    int k = kc * 32 + ((l2 >> 4) << 3);
    const float* s = ((mmct & 2) ? W_hh : W_ih) + (size_t)row * Dd + k;
    uint4 p;
    p.x = pk2(s[0], s[1]); p.y = pk2(s[2], s[3]);
    p.z = pk2(s[4], s[5]); p.w = pk2(s[6], s[7]);
    ldsW[i] = p;
  }

  const int w = tid >> 6, l = tid & 63;
  const int c = l & 15;
  const int rowbase = bh * 64 + w * 16;
  const int arow = rowbase + c;
  const int koff8 = l >> 4;
  const int r0 = ((c >> 3) << 10) | (gs << 3) | (c & 7);
  const int r1 = ((2 + (c >> 3)) << 10) | (gs << 3) | (c & 7);
  const float bias0 = b_ih[r0] + b_hh[r0];
  const float bias1 = b_ih[r1] + b_hh[r1];
  const int dim = (gs << 3) | (c & 7);
  const int crow = rowbase + (koff8 << 2);
  float creg[4];
  #pragma unroll
  for (int j = 0; j < 4; ++j) creg[j] = c0[(size_t)(crow + j) * Dd + dim];

  float* out_y = out;
  float* out_h = out + Bb;
  float* out_c = out + Bb + (size_t)Bb * Dd;

  int* myflag = &flags[bh * 512 + gs * 4 + w];
  const u64* fq = (const u64*)(flags + bh * 512);
  const int shbase = ((l & 15) >> 2) * 16;

  grid.sync();

  f32x4 pa0, pa1, pb0, pb1;
  {
    pa0 = f32x4{bias0, bias0, bias0, bias0};
    pa1 = f32x4{bias1, bias1, bias1, bias1};
    pb0 = f32x4{0.f, 0.f, 0.f, 0.f};
    pb1 = f32x4{0.f, 0.f, 0.f, 0.f};
    if (use_xbf) {
      const uint4* xA = (const uint4*)(xbf + ((size_t)0 * Bb + arow) * Dd + koff8 * 8);
      #pragma unroll
      for (int kc = 0; kc < 32; kc += 2) {
        uint4 ax0 = xA[kc * 4];
        uint4 ax1 = xA[(kc + 1) * 4];
        const int lb0 = kc * 256 + l, lb1 = (kc + 1) * 256 + l;
        pa0 = mfma_(as_bf(ax0), as_bf(ldsW[lb0]),      pa0);
        pa1 = mfma_(as_bf(ax0), as_bf(ldsW[lb0 + 64]), pa1);
        pb0 = mfma_(as_bf(ax1), as_bf(ldsW[lb1]),      pb0);
        pb1 = mfma_(as_bf(ax1), as_bf(ldsW[lb1 + 64]), pb1);
      }
    } else {
      const float* xF = inp + ((size_t)arow * Tt + 0) * Dd + koff8 * 8;
      #pragma unroll 4
      for (int kc = 0; kc < 32; ++kc) {
        const float* xs = xF + kc * 32;
        uint4 axu;
        axu.x = pk2(xs[0], xs[1]); axu.y = pk2(xs[2], xs[3]);
        axu.z = pk2(xs[4], xs[5]); axu.w = pk2(xs[6], xs[7]);
        const int lb = kc * 256 + l;
        pa0 = mfma_(as_bf(axu), as_bf(ldsW[lb]),      pa0);
        pa1 = mfma_(as_bf(axu), as_bf(ldsW[lb + 64]), pa1);
      }
    }
  }

  for (int t = 0; t < Tt; ++t) {
    const int rslot = RING ? t : (t & 1);
    const int wslot = RING ? (t + 1) : ((t + 1) & 1);

    if (w == 0) {
      int ok;
      do {
        u64 a = aload(&fq[l]);
        u64 b = aload(&fq[l + 64]);
        u64 c2 = aload(&fq[l + 128]);
        u64 d2 = aload(&fq[l + 192]);
        ok = ((int)a >= t) && ((int)(a >> 32) >= t) &&
             ((int)b >= t) && ((int)(b >> 32) >= t) &&
             ((int)c2 >= t) && ((int)(c2 >> 32) >= t) &&
             ((int)d2 >= t) && ((int)(d2 >> 32) >= t);
      } while (!__all(ok));
      __hip_atomic_store(&sent, t, __ATOMIC_RELEASE, __HIP_MEMORY_SCOPE_WORKGROUP);
    } else {
      while (__hip_atomic_load(&sent, __ATOMIC_ACQUIRE, __HIP_MEMORY_SCOPE_WORKGROUP) < t) {}
    }
    asm volatile("" ::: "memory");

    if constexpr (RING) {
      const uint4* hA4 = (const uint4*)(hbuf + (size_t)rslot * 131072);
      #pragma unroll
      for (int kc = 0; kc < 32; kc += 2) {
        uint4 h0u = hA4[(kc * 4 + koff8) * 128 + arow];
        uint4 h1u = hA4[((kc + 1) * 4 + koff8) * 128 + arow];
        const int lb0 = kc * 256 + l, lb1 = (kc + 1) * 256 + l;
        pa0 = mfma_(as_bf(h0u), as_bf(ldsW[lb0 + 128]), pa0);
        pa1 = mfma_(as_bf(h0u), as_bf(ldsW[lb0 + 192]), pa1);
        pb0 = mfma_(as_bf(h1u), as_bf(ldsW[lb1 + 128]), pb0);
        pb1 = mfma_(as_bf(h1u), as_bf(ldsW[lb1 + 192]), pb1);
      }
    } else {
      const u64* hA = (const u64*)hbuf + (size_t)rslot * 32768;
      #pragma unroll
      for (int kc = 0; kc < 32; kc += 2) {
        const int hi0 = (kc * 4 + koff8) * 256 + arow * 2;
        const int hi1 = ((kc + 1) * 4 + koff8) * 256 + arow * 2;
        union { u64 q[2]; uint4 p4; } h0u, h1u;
        h0u.q[0] = aload(&hA[hi0]); h0u.q[1] = aload(&hA[hi0 + 1]);
        h1u.q[0] = aload(&hA[hi1]); h1u.q[1] = aload(&hA[hi1 + 1]);
        const int lb0 = kc * 256 + l, lb1 = (kc + 1) * 256 + l;
        pa0 = mfma_(as_bf(h0u.p4), as_bf(ldsW[lb0 + 128]), pa0);
        pa1 = mfma_(as_bf(h0u.p4), as_bf(ldsW[lb0 + 192]), pa1);
        pb0 = mfma_(as_bf(h1u.p4), as_bf(ldsW[lb1 + 128]), pb0);
        pb1 = mfma_(as_bf(h1u.p4), as_bf(ldsW[lb1 + 192]), pb1);
      }
    }
    f32x4 acc0 = pa0 + pb0;
    f32x4 acc1 = pa1 + pb1;

    float fo0[4], fo1[4];
    #pragma unroll
    for (int j = 0; j < 4; ++j) {
      fo0[j] = __shfl_xor(acc0[j], 8);
      fo1[j] = __shfl_xor(acc1[j], 8);
    }
    unsigned int bfu0 = 0, bfu1 = 0, bfu2 = 0, bfu3 = 0;
    if (c < 8) {
      float hnv[4];
      #pragma unroll
      for (int j = 0; j < 4; ++j) {
        float iv = sigm(acc0[j]);
        float fv = sigm(fo0[j]);
        float gv = tanh_s(acc1[j]);
        float ov = sigm(fo1[j]);
        float cn = fv * creg[j] + iv * gv;
        float hn2 = ov * tanh_s(cn);
        creg[j] = cn;
        hnv[j] = hn2;
        if (t == Tt - 1) {
          size_t off = (size_t)(crow + j) * Dd + dim;
          __hip_atomic_store(&out_h[off], hn2, __ATOMIC_RELAXED, __HIP_MEMORY_SCOPE_AGENT);
          __hip_atomic_store(&out_c[off], cn, __ATOMIC_RELAXED, __HIP_MEMORY_SCOPE_AGENT);
        }
      }
      bfu0 = f2bf(hnv[0]); bfu1 = f2bf(hnv[1]);
      bfu2 = f2bf(hnv[2]); bfu3 = f2bf(hnv[3]);
    }

    unsigned int w0 = 0, w1 = 0, w2 = 0, w3 = 0;
    #pragma unroll
    for (int j = 0; j < 4; ++j) {
      unsigned int src = (j == 0) ? bfu0 : (j == 1) ? bfu1 : (j == 2) ? bfu2 : bfu3;
      unsigned int lo0 = __shfl((int)src, shbase + 0);
      unsigned int hi0g = __shfl((int)src, shbase + 1);
      unsigned int lo1 = __shfl((int)src, shbase + 2);
      unsigned int hi1g = __shfl((int)src, shbase + 3);
      unsigned int lo2 = __shfl((int)src, shbase + 4);
      unsigned int hi2g = __shfl((int)src, shbase + 5);
      unsigned int lo3 = __shfl((int)src, shbase + 6);
      unsigned int hi3g = __shfl((int)src, shbase + 7);
      bool mine = ((l & 3) == j);
      if (mine) {
        w0 = lo0 | (hi0g << 16);
        w1 = lo1 | (hi1g << 16);
        w2 = lo2 | (hi2g << 16);
        w3 = lo3 | (hi3g << 16);
      }
    }
    if (l < 16) {
      u32x4 val = {w0, w1, w2, w3};
      unsigned short* hw = hbuf + (size_t)wslot * 131072
                           + (size_t)gs * 1024 + (size_t)(rowbase + l) * 8;
      asm volatile("global_store_dwordx4 %0, %1, off sc0 sc1"
                   :: "v"(hw), "v"(val) : "memory");
    }

    pa0 = f32x4{bias0, bias0, bias0, bias0};
    pa1 = f32x4{bias1, bias1, bias1, bias1};
    pb0 = f32x4{0.f, 0.f, 0.f, 0.f};
    pb1 = f32x4{0.f, 0.f, 0.f, 0.f};
    if (t < Tt - 1) {
      if (use_xbf) {
        const uint4* xA = (const uint4*)(xbf + ((size_t)(t + 1) * Bb + arow) * Dd + koff8 * 8);
        #pragma unroll
        for (int kc = 0; kc < 32; kc += 2) {
          uint4 ax0 = xA[kc * 4];
          uint4 ax1 = xA[(kc + 1) * 4];
          const int lb0 = kc * 256 + l, lb1 = (kc + 1) * 256 + l;
          pa0 = mfma_(as_bf(ax0), as_bf(ldsW[lb0]),      pa0);
          pa1 = mfma_(as_bf(ax0), as_bf(ldsW[lb0 + 64]), pa1);
          pb0 = mfma_(as_bf(ax1), as_bf(ldsW[lb1]),      pb0);
          pb1 = mfma_(as_bf(ax1), as_bf(ldsW[lb1 + 64]), pb1);
        }
      } else {
        const float* xF = inp + ((size_t)arow * Tt + (t + 1)) * Dd + koff8 * 8;
        #pragma unroll 4
        for (int kc = 0; kc < 32; ++kc) {
          const float* xs = xF + kc * 32;
          uint4 axu;
          axu.x = pk2(xs[0], xs[1]); axu.y = pk2(xs[2], xs[3]);
          axu.z = pk2(xs[4], xs[5]); axu.w = pk2(xs[6], xs[7]);
          const int lb = kc * 256 + l;
          pa0 = mfma_(as_bf(axu), as_bf(ldsW[lb]),      pa0);
          pa1 = mfma_(as_bf(axu), as_bf(ldsW[lb + 64]), pa1);
        }
      }
    }

    asm volatile("s_waitcnt vmcnt(0)" ::: "memory");
    if (l == 0)
      __hip_atomic_store(myflag, t + 1, __ATOMIC_RELAXED, __HIP_MEMORY_SCOPE_AGENT);
  }

  if (wg < Bb) {
    {
      const u64* fa = (const u64*)flags;
      int ok;
      do {
        ok = 1;
        #pragma unroll
        for (int r = 0; r < 8; ++r) {
          u64 v = aload(&fa[l + r * 64]);
          ok &= ((int)v >= Tt) && ((int)(v >> 32) >= Tt);
        }
      } while (!__all(ok));
    }
    const u64* hr = (const u64*)(out_h + (size_t)wg * Dd);
    float s = 0.f;
    for (int k = tid; k < Dd / 2; k += NTHR) {
      u64 v = aload(&hr[k]);
      union { u64 u; float f[2]; } q; q.u = v;
      s += q.f[0] * fc_w[2 * k] + q.f[1] * fc_w[2 * k + 1];
    }
    #pragma unroll
    for (int off = 32; off > 0; off >>= 1) s += __shfl_down(s, off);
    if (l == 0) red[w] = s;
    __syncthreads();
    if (tid == 0) {
      float tot = red[0] + red[1] + red[2] + red[3] + fc_b[0];
      out_y[wg] = sigm(tot);
    }
  }
}

extern "C" void kernel_launch(void* const* d_in, const int* in_sizes, int n_in,
                              void* d_out, int out_size, void* d_ws, size_t ws_size,
                              hipStream_t stream) {
  (void)in_sizes; (void)n_in; (void)out_size;
  const float* inp  = (const float*)d_in[0];
  const float* h0   = (const float*)d_in[1];
  const float* c0   = (const float*)d_in[2];
  const float* W_ih = (const float*)d_in[3];
  const float* W_hh = (const float*)d_in[4];
  const float* b_ih = (const float*)d_in[5];
  const float* b_hh = (const float*)d_in[6];
  const float* fc_w = (const float*)d_in[7];
  const float* fc_b = (const float*)d_in[8];
  float* out = (float*)d_out;

  const size_t fbytes  = 16384;
  const size_t slot    = (size_t)Bb * Dd * 2;            // 256 KB
  const size_t ring1   = (size_t)(Tt + 1) * slot;        // 67.4 MB
  const size_t ring0   = 2 * slot;                       // 512 KB
  const size_t xbytes  = (size_t)Tt * Bb * Dd * 2;       // 64 MB
  const size_t xgbytes = (size_t)Tt * 4096 * Bb * 2;     // 256 MB

  int* flags = (int*)d_ws;
  unsigned short* hbuf = (unsigned short*)((char*)d_ws + fbytes);

  if (ws_size >= fbytes + ring1 + xgbytes + xbytes) {
    // ======== Tier X: precompute x-gates, slim scan ========
    unsigned short* xg  = (unsigned short*)((char*)d_ws + fbytes + ring1);
    unsigned short* xbf = (unsigned short*)((char*)d_ws + fbytes + ring1 + xgbytes);

    hipLaunchKernelGGL(xcvt_kernel, dim3(2048), dim3(256), 0, stream, inp, xbf);

    (void)hipFuncSetAttribute((const void*)xg_kernel,
                              hipFuncAttributeMaxDynamicSharedMemorySize, 65536);
    hipLaunchKernelGGL(xg_kernel, dim3(256), dim3(256), 65536, stream,
                       xbf, W_ih, b_ih, b_hh, xg);

    (void)hipFuncSetAttribute((const void*)lstm_scan_kernel,
                              hipFuncAttributeMaxDynamicSharedMemorySize, 65536);
    const unsigned short* xg_c = xg;
    void* kargs[] = {(void*)&h0, (void*)&c0, (void*)&W_hh, (void*)&fc_w,
                     (void*)&fc_b, (void*)&out, (void*)&flags, (void*)&hbuf,
                     (void*)&xg_c};
    (void)hipLaunchCooperativeKernel((void*)lstm_scan_kernel, dim3(NWG), dim3(NTHR),
                                     kargs, 65536u, stream);
    return;
  }

  // ======== Fallback tiers: mono kernel (R10 structure) ========
  int ring, use_xbf;
  size_t rbytes;
  if (ws_size >= fbytes + ring1 + xbytes)      { ring = 1; use_xbf = 1; rbytes = ring1; }
  else if (ws_size >= fbytes + ring1)          { ring = 1; use_xbf = 0; rbytes = ring1; }
  else if (ws_size >= fbytes + ring0 + xbytes) { ring = 0; use_xbf = 1; rbytes = ring0; }
  else                                         { ring = 0; use_xbf = 0; rbytes = ring0; }

  unsigned short* xbf = (unsigned short*)((char*)d_ws + fbytes + rbytes);

  void* kfn = ring ? (void*)lstm_kernel_mono<1> : (void*)lstm_kernel_mono<0>;
  (void)hipFuncSetAttribute((const void*)kfn,
                            hipFuncAttributeMaxDynamicSharedMemorySize, 131072);

  void* kargs[] = {(void*)&inp, (void*)&h0, (void*)&c0, (void*)&W_ih, (void*)&W_hh,
                   (void*)&b_ih, (void*)&b_hh, (void*)&fc_w, (void*)&fc_b,
                   (void*)&out, (void*)&flags, (void*)&hbuf, (void*)&xbf, (void*)&use_xbf};
  (void)hipLaunchCooperativeKernel(kfn, dim3(NWG), dim3(NTHR),
                                   kargs, 131072u, stream);
}

// Round 13
// 3014.650 us; speedup vs baseline: 1.5331x; 1.3974x over previous
//
#include <hip/hip_runtime.h>
#include <hip/hip_cooperative_groups.h>

namespace cg = cooperative_groups;

#define Dd 1024
#define Bb 128
#define Tt 256
#define NWG 256
#define NTHR 256

typedef short bf16x8 __attribute__((ext_vector_type(8)));
typedef float f32x4 __attribute__((ext_vector_type(4)));
typedef unsigned int u32x4 __attribute__((ext_vector_type(4)));
typedef unsigned long long u64;

static __device__ __forceinline__ unsigned short f2bf(float x) {
  unsigned int u = __float_as_uint(x);
  u += 0x7fffu + ((u >> 16) & 1u);   // round-to-nearest-even
  return (unsigned short)(u >> 16);
}
static __device__ __forceinline__ unsigned int pk2(float a, float b) {
  return (unsigned int)f2bf(a) | ((unsigned int)f2bf(b) << 16);
}
static __device__ __forceinline__ bf16x8 as_bf(uint4 u) {
  union { uint4 u; bf16x8 v; } x; x.u = u; return x.v;
}
static __device__ __forceinline__ f32x4 mfma_(bf16x8 a, bf16x8 b, f32x4 c) {
  return __builtin_amdgcn_mfma_f32_16x16x32_bf16(a, b, c, 0, 0, 0);
}
static __device__ __forceinline__ float sigm(float x) { return 1.f / (1.f + __expf(-x)); }
static __device__ __forceinline__ float tanh_s(float x) { return 1.f - 2.f / (__expf(2.f * x) + 1.f); }
static __device__ __forceinline__ u64 aload(const u64* p) {
  return __hip_atomic_load(p, __ATOMIC_RELAXED, __HIP_MEMORY_SCOPE_AGENT);
}

// 256 WGs x 256 thr. WG = (batch-half bh, hidden-slice gs of 8 dims).
// LDS: W_ih+W_hh slices packed as MFMA B-fragments (128 KB, resident).
// h ring: 257 slots of 256KB; producers write-through (sc0 sc1), consumers
// use NORMAL cached loads. RING=0 fallback: coherent atomics, 2 slots.
// Flags: per-wave monotone ints flags[bh][gs][wave], plain agent stores;
// wave0-poll + LDS sentinel relay (R7 structure, measured best).
// Loop order (R13): wait(t) -> h-GEMM(t) [16-deep prefetch x2 rounds] ->
// pointwise -> transpose -> publish h(t+1) -> vmcnt(0) -> FLAG ASAP ->
// x-GEMM(t+1) (runs in the inter-WG skew window).
template<int RING>
__global__ void __launch_bounds__(NTHR, 1) lstm_kernel(
    const float* __restrict__ inp, const float* __restrict__ h0,
    const float* __restrict__ c0, const float* __restrict__ W_ih,
    const float* __restrict__ W_hh, const float* __restrict__ b_ih,
    const float* __restrict__ b_hh, const float* __restrict__ fc_w,
    const float* __restrict__ fc_b, float* __restrict__ out,
    int* __restrict__ flags, unsigned short* __restrict__ hbuf,
    unsigned short* __restrict__ xbf, int use_xbf)
{
  extern __shared__ uint4 ldsW[];   // 8192 fragments = 128 KB
  __shared__ float red[4];
  __shared__ int sent;

  const int tid = threadIdx.x;
  const int wg  = blockIdx.x;
  const int gid = wg * NTHR + tid;
  cg::grid_group grid = cg::this_grid();

  const int gs = wg >> 1;
  const int bh = wg & 1;

  // ---------- flag init: 4 per WG (one per wave), layout [bh][gs][wave]
  if (tid < 4)
    __hip_atomic_store(&flags[bh * 512 + gs * 4 + tid], 0,
                       __ATOMIC_RELAXED, __HIP_MEMORY_SCOPE_AGENT);
  if (tid == 0) sent = -1;

  // ---------- Phase A: inp [B,T,D] f32 -> xbf [T,B,D] bf16 ; h0 -> slot 0
  if (use_xbf) {
    for (int i = gid; i < Tt * Bb * (Dd / 8); i += NWG * NTHR) {
      int d8 = i & 127, b = (i >> 7) & 127, t = i >> 14;
      const float* s = inp + ((size_t)b * Tt + t) * Dd + d8 * 8;
      uint4 p;
      p.x = pk2(s[0], s[1]); p.y = pk2(s[2], s[3]);
      p.z = pk2(s[4], s[5]); p.w = pk2(s[6], s[7]);
      *(uint4*)(xbf + (size_t)i * 8) = p;
    }
  }
  // h0 [b][d] f32 -> slot0 [d>>3][b][d&7] bf16
  uint4* hb4w = (uint4*)hbuf;
  for (int i = gid; i < 128 * 128; i += NWG * NTHR) {
    int row = i & 127, gsl = i >> 7;
    const float* s = h0 + (size_t)row * Dd + gsl * 8;
    uint4 p;
    p.x = pk2(s[0], s[1]); p.y = pk2(s[2], s[3]);
    p.z = pk2(s[4], s[5]); p.w = pk2(s[6], s[7]);
    hb4w[gsl * 128 + row] = p;
  }

  // ---------- Phase B: pack W slices into LDS (bf16, fragment order)
  for (int i = tid; i < 8192; i += NTHR) {
    int l2 = i & 63, mmct = (i >> 6) & 3, kc = i >> 8;
    int cc = l2 & 15, ct = mmct & 1;
    int row = (((ct << 1) | (cc >> 3)) << 10) | (gs << 3) | (cc & 7);
    int k = kc * 32 + ((l2 >> 4) << 3);
    const float* s = ((mmct & 2) ? W_hh : W_ih) + (size_t)row * Dd + k;
    uint4 p;
    p.x = pk2(s[0], s[1]); p.y = pk2(s[2], s[3]);
    p.z = pk2(s[4], s[5]); p.w = pk2(s[6], s[7]);
    ldsW[i] = p;
  }

  // ---------- per-thread setup
  const int w = tid >> 6, l = tid & 63;
  const int c = l & 15;
  const int rowbase = bh * 64 + w * 16;
  const int arow = rowbase + c;
  const int koff8 = l >> 4;
  const int r0 = ((c >> 3) << 10) | (gs << 3) | (c & 7);
  const int r1 = ((2 + (c >> 3)) << 10) | (gs << 3) | (c & 7);
  const float bias0 = b_ih[r0] + b_hh[r0];
  const float bias1 = b_ih[r1] + b_hh[r1];
  const int dim = (gs << 3) | (c & 7);
  const int crow = rowbase + (koff8 << 2);
  float creg[4];
  #pragma unroll
  for (int j = 0; j < 4; ++j) creg[j] = c0[(size_t)(crow + j) * Dd + dim];

  float* out_y = out;
  float* out_h = out + Bb;
  float* out_c = out + Bb + (size_t)Bb * Dd;

  int* myflag = &flags[bh * 512 + gs * 4 + w];
  const u64* fq = (const u64*)(flags + bh * 512);
  const int shbase = ((l & 15) >> 2) * 16;

  grid.sync();   // one-time: publish flag init, xbf, slot0

  // ---------- x accumulators, carried across iterations
  f32x4 pa0, pa1, pb0, pb1;

  // prologue: x-part for t = 0
  {
    pa0 = f32x4{bias0, bias0, bias0, bias0};
    pa1 = f32x4{bias1, bias1, bias1, bias1};
    pb0 = f32x4{0.f, 0.f, 0.f, 0.f};
    pb1 = f32x4{0.f, 0.f, 0.f, 0.f};
    if (use_xbf) {
      const uint4* xA = (const uint4*)(xbf + ((size_t)0 * Bb + arow) * Dd + koff8 * 8);
      #pragma unroll
      for (int kc = 0; kc < 32; kc += 2) {
        uint4 ax0 = xA[kc * 4];
        uint4 ax1 = xA[(kc + 1) * 4];
        const int lb0 = kc * 256 + l, lb1 = (kc + 1) * 256 + l;
        pa0 = mfma_(as_bf(ax0), as_bf(ldsW[lb0]),      pa0);
        pa1 = mfma_(as_bf(ax0), as_bf(ldsW[lb0 + 64]), pa1);
        pb0 = mfma_(as_bf(ax1), as_bf(ldsW[lb1]),      pb0);
        pb1 = mfma_(as_bf(ax1), as_bf(ldsW[lb1 + 64]), pb1);
      }
    } else {
      const float* xF = inp + ((size_t)arow * Tt + 0) * Dd + koff8 * 8;
      #pragma unroll 4
      for (int kc = 0; kc < 32; ++kc) {
        const float* xs = xF + kc * 32;
        uint4 axu;
        axu.x = pk2(xs[0], xs[1]); axu.y = pk2(xs[2], xs[3]);
        axu.z = pk2(xs[4], xs[5]); axu.w = pk2(xs[6], xs[7]);
        const int lb = kc * 256 + l;
        pa0 = mfma_(as_bf(axu), as_bf(ldsW[lb]),      pa0);
        pa1 = mfma_(as_bf(axu), as_bf(ldsW[lb + 64]), pa1);
      }
    }
  }

  // ---------- sequential scan
  for (int t = 0; t < Tt; ++t) {
    const int rslot = RING ? t : (t & 1);
    const int wslot = RING ? (t + 1) : ((t + 1) & 1);

    // ---- wait for h(t)
    if (w == 0) {
      int ok;
      do {
        u64 a = aload(&fq[l]);
        u64 b = aload(&fq[l + 64]);
        u64 c2 = aload(&fq[l + 128]);
        u64 d2 = aload(&fq[l + 192]);
        ok = ((int)a >= t) && ((int)(a >> 32) >= t) &&
             ((int)b >= t) && ((int)(b >> 32) >= t) &&
             ((int)c2 >= t) && ((int)(c2 >> 32) >= t) &&
             ((int)d2 >= t) && ((int)(d2 >> 32) >= t);
      } while (!__all(ok));
      __hip_atomic_store(&sent, t, __ATOMIC_RELEASE, __HIP_MEMORY_SCOPE_WORKGROUP);
    } else {
      while (__hip_atomic_load(&sent, __ATOMIC_ACQUIRE, __HIP_MEMORY_SCOPE_WORKGROUP) < t) {}
    }
    asm volatile("" ::: "memory");

    // ---- h-part: 16-deep prefetch, 2 rounds (statically indexed)
    if constexpr (RING) {
      const uint4* hA4 = (const uint4*)(hbuf + (size_t)rslot * 131072);
      #pragma unroll
      for (int rr = 0; rr < 2; ++rr) {
        uint4 hv[16];
        #pragma unroll
        for (int i = 0; i < 16; ++i)
          hv[i] = hA4[((rr * 16 + i) * 4 + koff8) * 128 + arow];
        #pragma unroll
        for (int i = 0; i < 16; i += 2) {
          const int kc = rr * 16 + i;
          const int lb0 = kc * 256 + l, lb1 = (kc + 1) * 256 + l;
          pa0 = mfma_(as_bf(hv[i]),     as_bf(ldsW[lb0 + 128]), pa0);
          pa1 = mfma_(as_bf(hv[i]),     as_bf(ldsW[lb0 + 192]), pa1);
          pb0 = mfma_(as_bf(hv[i + 1]), as_bf(ldsW[lb1 + 128]), pb0);
          pb1 = mfma_(as_bf(hv[i + 1]), as_bf(ldsW[lb1 + 192]), pb1);
        }
      }
    } else {
      const u64* hA = (const u64*)hbuf + (size_t)rslot * 32768;
      #pragma unroll
      for (int kc = 0; kc < 32; kc += 2) {
        const int hi0 = (kc * 4 + koff8) * 256 + arow * 2;
        const int hi1 = ((kc + 1) * 4 + koff8) * 256 + arow * 2;
        union { u64 q[2]; uint4 p4; } h0u, h1u;
        h0u.q[0] = aload(&hA[hi0]); h0u.q[1] = aload(&hA[hi0 + 1]);
        h1u.q[0] = aload(&hA[hi1]); h1u.q[1] = aload(&hA[hi1 + 1]);
        const int lb0 = kc * 256 + l, lb1 = (kc + 1) * 256 + l;
        pa0 = mfma_(as_bf(h0u.p4), as_bf(ldsW[lb0 + 128]), pa0);
        pa1 = mfma_(as_bf(h0u.p4), as_bf(ldsW[lb0 + 192]), pa1);
        pb0 = mfma_(as_bf(h1u.p4), as_bf(ldsW[lb1 + 128]), pb0);
        pb1 = mfma_(as_bf(h1u.p4), as_bf(ldsW[lb1 + 192]), pb1);
      }
    }
    f32x4 acc0 = pa0 + pb0;
    f32x4 acc1 = pa1 + pb1;

    // ---- pointwise (acc0: i|f, acc1: g|o split at col 8)
    float fo0[4], fo1[4];
    #pragma unroll
    for (int j = 0; j < 4; ++j) {
      fo0[j] = __shfl_xor(acc0[j], 8);
      fo1[j] = __shfl_xor(acc1[j], 8);
    }
    unsigned int bfu0 = 0, bfu1 = 0, bfu2 = 0, bfu3 = 0;
    if (c < 8) {
      float hnv[4];
      #pragma unroll
      for (int j = 0; j < 4; ++j) {
        float iv = sigm(acc0[j]);
        float fv = sigm(fo0[j]);
        float gv = tanh_s(acc1[j]);
        float ov = sigm(fo1[j]);
        float cn = fv * creg[j] + iv * gv;
        float hn2 = ov * tanh_s(cn);
        creg[j] = cn;
        hnv[j] = hn2;
        if (t == Tt - 1) {
          size_t off = (size_t)(crow + j) * Dd + dim;
          __hip_atomic_store(&out_h[off], hn2, __ATOMIC_RELAXED, __HIP_MEMORY_SCOPE_AGENT);
          __hip_atomic_store(&out_c[off], cn, __ATOMIC_RELAXED, __HIP_MEMORY_SCOPE_AGENT);
        }
      }
      bfu0 = f2bf(hnv[0]); bfu1 = f2bf(hnv[1]);
      bfu2 = f2bf(hnv[2]); bfu3 = f2bf(hnv[3]);
    }

    // ---- in-wave transpose: lane r<16 gathers row (rowbase+r), dims 0..7
    unsigned int w0 = 0, w1 = 0, w2 = 0, w3 = 0;
    #pragma unroll
    for (int j = 0; j < 4; ++j) {
      unsigned int src = (j == 0) ? bfu0 : (j == 1) ? bfu1 : (j == 2) ? bfu2 : bfu3;
      unsigned int lo0 = __shfl((int)src, shbase + 0);
      unsigned int hi0g = __shfl((int)src, shbase + 1);
      unsigned int lo1 = __shfl((int)src, shbase + 2);
      unsigned int hi1g = __shfl((int)src, shbase + 3);
      unsigned int lo2 = __shfl((int)src, shbase + 4);
      unsigned int hi2g = __shfl((int)src, shbase + 5);
      unsigned int lo3 = __shfl((int)src, shbase + 6);
      unsigned int hi3g = __shfl((int)src, shbase + 7);
      bool mine = ((l & 3) == j);
      if (mine) {
        w0 = lo0 | (hi0g << 16);
        w1 = lo1 | (hi1g << 16);
        w2 = lo2 | (hi2g << 16);
        w3 = lo3 | (hi3g << 16);
      }
    }
    // ---- publish h(t+1), drain, raise flag ASAP
    if (l < 16) {
      u32x4 val = {w0, w1, w2, w3};
      unsigned short* hw = hbuf + (size_t)wslot * 131072
                           + (size_t)gs * 1024 + (size_t)(rowbase + l) * 8;
      asm volatile("global_store_dwordx4 %0, %1, off sc0 sc1"
                   :: "v"(hw), "v"(val) : "memory");
    }
    asm volatile("s_waitcnt vmcnt(0)" ::: "memory");  // h(t+1) globally visible
    if (l == 0)
      __hip_atomic_store(myflag, t + 1, __ATOMIC_RELAXED, __HIP_MEMORY_SCOPE_AGENT);

    // ---- x-part for step t+1 AFTER the flag (hides in inter-WG skew)
    pa0 = f32x4{bias0, bias0, bias0, bias0};
    pa1 = f32x4{bias1, bias1, bias1, bias1};
    pb0 = f32x4{0.f, 0.f, 0.f, 0.f};
    pb1 = f32x4{0.f, 0.f, 0.f, 0.f};
    if (t < Tt - 1) {
      if (use_xbf) {
        const uint4* xA = (const uint4*)(xbf + ((size_t)(t + 1) * Bb + arow) * Dd + koff8 * 8);
        #pragma unroll
        for (int kc = 0; kc < 32; kc += 2) {
          uint4 ax0 = xA[kc * 4];
          uint4 ax1 = xA[(kc + 1) * 4];
          const int lb0 = kc * 256 + l, lb1 = (kc + 1) * 256 + l;
          pa0 = mfma_(as_bf(ax0), as_bf(ldsW[lb0]),      pa0);
          pa1 = mfma_(as_bf(ax0), as_bf(ldsW[lb0 + 64]), pa1);
          pb0 = mfma_(as_bf(ax1), as_bf(ldsW[lb1]),      pb0);
          pb1 = mfma_(as_bf(ax1), as_bf(ldsW[lb1 + 64]), pb1);
        }
      } else {
        const float* xF = inp + ((size_t)arow * Tt + (t + 1)) * Dd + koff8 * 8;
        #pragma unroll 4
        for (int kc = 0; kc < 32; ++kc) {
          const float* xs = xF + kc * 32;
          uint4 axu;
          axu.x = pk2(xs[0], xs[1]); axu.y = pk2(xs[2], xs[3]);
          axu.z = pk2(xs[4], xs[5]); axu.w = pk2(xs[6], xs[7]);
          const int lb = kc * 256 + l;
          pa0 = mfma_(as_bf(axu), as_bf(ldsW[lb]),      pa0);
          pa1 = mfma_(as_bf(axu), as_bf(ldsW[lb + 64]), pa1);
        }
      }
    }
  }

  // ---------- fc head: yhat[b] = sigmoid(hx[b,:] . fc_w + fc_b)
  if (wg < Bb) {
    {
      const u64* fa = (const u64*)flags;   // 512 u64 total
      int ok;
      do {
        ok = 1;
        #pragma unroll
        for (int r = 0; r < 8; ++r) {
          u64 v = aload(&fa[l + r * 64]);
          ok &= ((int)v >= Tt) && ((int)(v >> 32) >= Tt);
        }
      } while (!__all(ok));
    }
    const u64* hr = (const u64*)(out_h + (size_t)wg * Dd);
    float s = 0.f;
    for (int k = tid; k < Dd / 2; k += NTHR) {
      u64 v = aload(&hr[k]);
      union { u64 u; float f[2]; } q; q.u = v;
      s += q.f[0] * fc_w[2 * k] + q.f[1] * fc_w[2 * k + 1];
    }
    #pragma unroll
    for (int off = 32; off > 0; off >>= 1) s += __shfl_down(s, off);
    if (l == 0) red[w] = s;
    __syncthreads();
    if (tid == 0) {
      float tot = red[0] + red[1] + red[2] + red[3] + fc_b[0];
      out_y[wg] = sigm(tot);
    }
  }
}

extern "C" void kernel_launch(void* const* d_in, const int* in_sizes, int n_in,
                              void* d_out, int out_size, void* d_ws, size_t ws_size,
                              hipStream_t stream) {
  (void)in_sizes; (void)n_in; (void)out_size;
  const float* inp  = (const float*)d_in[0];
  const float* h0   = (const float*)d_in[1];
  const float* c0   = (const float*)d_in[2];
  const float* W_ih = (const float*)d_in[3];
  const float* W_hh = (const float*)d_in[4];
  const float* b_ih = (const float*)d_in[5];
  const float* b_hh = (const float*)d_in[6];
  const float* fc_w = (const float*)d_in[7];
  const float* fc_b = (const float*)d_in[8];
  float* out = (float*)d_out;

  const size_t fbytes = 16384;                         // flags (4 KB used)
  const size_t slot   = (size_t)Bb * Dd * 2;           // 256 KB
  const size_t ring1  = (size_t)(Tt + 1) * slot;       // 67.4 MB
  const size_t ring0  = 2 * slot;                      // 512 KB
  const size_t xbytes = (size_t)Tt * Bb * Dd * 2;      // 64 MB

  int ring, use_xbf;
  size_t rbytes;
  if (ws_size >= fbytes + ring1 + xbytes)      { ring = 1; use_xbf = 1; rbytes = ring1; }
  else if (ws_size >= fbytes + ring1)          { ring = 1; use_xbf = 0; rbytes = ring1; }
  else if (ws_size >= fbytes + ring0 + xbytes) { ring = 0; use_xbf = 1; rbytes = ring0; }
  else                                         { ring = 0; use_xbf = 0; rbytes = ring0; }

  int* flags = (int*)d_ws;
  unsigned short* hbuf = (unsigned short*)((char*)d_ws + fbytes);
  unsigned short* xbf  = (unsigned short*)((char*)d_ws + fbytes + rbytes);

  void* kfn = ring ? (void*)lstm_kernel<1> : (void*)lstm_kernel<0>;
  (void)hipFuncSetAttribute((const void*)kfn,
                            hipFuncAttributeMaxDynamicSharedMemorySize, 131072);

  void* kargs[] = {(void*)&inp, (void*)&h0, (void*)&c0, (void*)&W_ih, (void*)&W_hh,
                   (void*)&b_ih, (void*)&b_hh, (void*)&fc_w, (void*)&fc_b,
                   (void*)&out, (void*)&flags, (void*)&hbuf, (void*)&xbf, (void*)&use_xbf};
  (void)hipLaunchCooperativeKernel(kfn, dim3(NWG), dim3(NTHR),
                                   kargs, 131072u, stream);
}

// Round 14
// 2843.324 us; speedup vs baseline: 1.6255x; 1.0603x over previous
//
#include <hip/hip_runtime.h>
#include <hip/hip_cooperative_groups.h>

namespace cg = cooperative_groups;

#define Dd 1024
#define Bb 128
#define Tt 256
#define NWG 256
#define NTHR 256

typedef short bf16x8 __attribute__((ext_vector_type(8)));
typedef float f32x4 __attribute__((ext_vector_type(4)));
typedef unsigned int u32x4 __attribute__((ext_vector_type(4)));
typedef unsigned long long u64;

static __device__ __forceinline__ unsigned short f2bf(float x) {
  unsigned int u = __float_as_uint(x);
  u += 0x7fffu + ((u >> 16) & 1u);   // round-to-nearest-even
  return (unsigned short)(u >> 16);
}
static __device__ __forceinline__ unsigned int pk2(float a, float b) {
  return (unsigned int)f2bf(a) | ((unsigned int)f2bf(b) << 16);
}
static __device__ __forceinline__ bf16x8 as_bf(uint4 u) {
  union { uint4 u; bf16x8 v; } x; x.u = u; return x.v;
}
static __device__ __forceinline__ f32x4 mfma_(bf16x8 a, bf16x8 b, f32x4 c) {
  return __builtin_amdgcn_mfma_f32_16x16x32_bf16(a, b, c, 0, 0, 0);
}
static __device__ __forceinline__ float sigm(float x) { return 1.f / (1.f + __expf(-x)); }
static __device__ __forceinline__ float tanh_s(float x) { return 1.f - 2.f / (__expf(2.f * x) + 1.f); }
static __device__ __forceinline__ u64 aload(const u64* p) {
  return __hip_atomic_load(p, __ATOMIC_RELAXED, __HIP_MEMORY_SCOPE_AGENT);
}

// R7 configuration — measured best (2878 us).
// 256 WGs x 256 thr. WG = (batch-half bh, hidden-slice gs of 8 dims).
// LDS: W_ih+W_hh slices packed as MFMA B-fragments (128 KB, resident).
// h ring: 257 slots of 256KB (RING=1); producers write-through (sc0 sc1),
// consumers use NORMAL cached loads (single-writer slots, read-after-flag).
// RING=0 fallback: coherent-point atomic loads on a 2-slot buffer.
// Flags: per-wave monotone ints flags[bh][gs][wave], plain agent stores;
// wave0 polls this half's 256 u64, relays via LDS sentinel.
// Loop: x-GEMM(t) -> wait(t) -> h-GEMM(t) -> pointwise -> transpose ->
// publish h(t+1) (dwordx4 sc0 sc1) -> vmcnt(0) -> flag(t+1).
template<int RING>
__global__ void __launch_bounds__(NTHR, 1) lstm_kernel(
    const float* __restrict__ inp, const float* __restrict__ h0,
    const float* __restrict__ c0, const float* __restrict__ W_ih,
    const float* __restrict__ W_hh, const float* __restrict__ b_ih,
    const float* __restrict__ b_hh, const float* __restrict__ fc_w,
    const float* __restrict__ fc_b, float* __restrict__ out,
    int* __restrict__ flags, unsigned short* __restrict__ hbuf,
    unsigned short* __restrict__ xbf, int use_xbf)
{
  extern __shared__ uint4 ldsW[];   // 8192 fragments = 128 KB
  __shared__ float red[4];
  __shared__ int sent;

  const int tid = threadIdx.x;
  const int wg  = blockIdx.x;
  const int gid = wg * NTHR + tid;
  cg::grid_group grid = cg::this_grid();

  const int gs = wg >> 1;
  const int bh = wg & 1;

  // ---------- flag init: 4 per WG (one per wave), layout [bh][gs][wave]
  if (tid < 4)
    __hip_atomic_store(&flags[bh * 512 + gs * 4 + tid], 0,
                       __ATOMIC_RELAXED, __HIP_MEMORY_SCOPE_AGENT);
  if (tid == 0) sent = -1;

  // ---------- Phase A: inp [B,T,D] f32 -> xbf [T,B,D] bf16 ; h0 -> slot 0
  if (use_xbf) {
    for (int i = gid; i < Tt * Bb * (Dd / 8); i += NWG * NTHR) {
      int d8 = i & 127, b = (i >> 7) & 127, t = i >> 14;
      const float* s = inp + ((size_t)b * Tt + t) * Dd + d8 * 8;
      uint4 p;
      p.x = pk2(s[0], s[1]); p.y = pk2(s[2], s[3]);
      p.z = pk2(s[4], s[5]); p.w = pk2(s[6], s[7]);
      *(uint4*)(xbf + (size_t)i * 8) = p;
    }
  }
  // h0 [b][d] f32 -> slot0 [d>>3][b][d&7] bf16
  uint4* hb4w = (uint4*)hbuf;
  for (int i = gid; i < 128 * 128; i += NWG * NTHR) {
    int row = i & 127, gsl = i >> 7;
    const float* s = h0 + (size_t)row * Dd + gsl * 8;
    uint4 p;
    p.x = pk2(s[0], s[1]); p.y = pk2(s[2], s[3]);
    p.z = pk2(s[4], s[5]); p.w = pk2(s[6], s[7]);
    hb4w[gsl * 128 + row] = p;
  }

  // ---------- Phase B: pack W slices into LDS (bf16, fragment order)
  for (int i = tid; i < 8192; i += NTHR) {
    int l2 = i & 63, mmct = (i >> 6) & 3, kc = i >> 8;
    int cc = l2 & 15, ct = mmct & 1;
    int row = (((ct << 1) | (cc >> 3)) << 10) | (gs << 3) | (cc & 7);
    int k = kc * 32 + ((l2 >> 4) << 3);
    const float* s = ((mmct & 2) ? W_hh : W_ih) + (size_t)row * Dd + k;
    uint4 p;
    p.x = pk2(s[0], s[1]); p.y = pk2(s[2], s[3]);
    p.z = pk2(s[4], s[5]); p.w = pk2(s[6], s[7]);
    ldsW[i] = p;
  }

  // ---------- per-thread setup
  const int w = tid >> 6, l = tid & 63;
  const int c = l & 15;
  const int rowbase = bh * 64 + w * 16;
  const int arow = rowbase + c;                 // A-fragment batch row
  const int koff8 = l >> 4;                     // k sub-chunk (0..3) within 32
  const int r0 = ((c >> 3) << 10) | (gs << 3) | (c & 7);        // i/f row
  const int r1 = ((2 + (c >> 3)) << 10) | (gs << 3) | (c & 7);  // g/o row
  const float bias0 = b_ih[r0] + b_hh[r0];
  const float bias1 = b_ih[r1] + b_hh[r1];
  const int dim = (gs << 3) | (c & 7);
  const int crow = rowbase + (koff8 << 2);      // C/D fragment row base
  float creg[4];
  #pragma unroll
  for (int j = 0; j < 4; ++j) creg[j] = c0[(size_t)(crow + j) * Dd + dim];

  float* out_y = out;
  float* out_h = out + Bb;
  float* out_c = out + Bb + (size_t)Bb * Dd;

  int* myflag = &flags[bh * 512 + gs * 4 + w];
  const u64* fq = (const u64*)(flags + bh * 512);  // 256 u64 = this half
  const int shbase = ((l & 15) >> 2) * 16;         // shfl source base

  grid.sync();   // one-time: publish flag init, xbf, slot0 (release+acquire)

  // ---------- sequential scan (no syncthreads, no fences)
  for (int t = 0; t < Tt; ++t) {
    const int rslot = RING ? t : (t & 1);
    const int wslot = RING ? (t + 1) : ((t + 1) & 1);

    // ---- x-part: no dependency on h(t)
    f32x4 xa0 = {bias0, bias0, bias0, bias0};
    f32x4 xa1 = {bias1, bias1, bias1, bias1};
    f32x4 xb0 = {0.f, 0.f, 0.f, 0.f};
    f32x4 xb1 = {0.f, 0.f, 0.f, 0.f};

    if (use_xbf) {
      const uint4* xA = (const uint4*)(xbf + ((size_t)t * Bb + arow) * Dd + koff8 * 8);
      #pragma unroll
      for (int kc = 0; kc < 32; kc += 2) {
        uint4 ax0 = xA[kc * 4];
        uint4 ax1 = xA[(kc + 1) * 4];
        const int lb0 = kc * 256 + l, lb1 = (kc + 1) * 256 + l;
        xa0 = mfma_(as_bf(ax0), as_bf(ldsW[lb0]),      xa0);
        xa1 = mfma_(as_bf(ax0), as_bf(ldsW[lb0 + 64]), xa1);
        xb0 = mfma_(as_bf(ax1), as_bf(ldsW[lb1]),      xb0);
        xb1 = mfma_(as_bf(ax1), as_bf(ldsW[lb1 + 64]), xb1);
      }
    } else {
      const float* xF = inp + ((size_t)arow * Tt + t) * Dd + koff8 * 8;
      #pragma unroll 4
      for (int kc = 0; kc < 32; ++kc) {
        const float* xs = xF + kc * 32;
        uint4 axu;
        axu.x = pk2(xs[0], xs[1]); axu.y = pk2(xs[2], xs[3]);
        axu.z = pk2(xs[4], xs[5]); axu.w = pk2(xs[6], xs[7]);
        const int lb = kc * 256 + l;
        xa0 = mfma_(as_bf(axu), as_bf(ldsW[lb]),      xa0);
        xa1 = mfma_(as_bf(axu), as_bf(ldsW[lb + 64]), xa1);
      }
    }

    // ---- wait for h(t): wave 0 polls global flags, others spin LDS sentinel
    if (w == 0) {
      int ok;
      do {
        u64 a = aload(&fq[l]);
        u64 b = aload(&fq[l + 64]);
        u64 c2 = aload(&fq[l + 128]);
        u64 d2 = aload(&fq[l + 192]);
        ok = ((int)a >= t) && ((int)(a >> 32) >= t) &&
             ((int)b >= t) && ((int)(b >> 32) >= t) &&
             ((int)c2 >= t) && ((int)(c2 >> 32) >= t) &&
             ((int)d2 >= t) && ((int)(d2 >> 32) >= t);
      } while (!__all(ok));
      __hip_atomic_store(&sent, t, __ATOMIC_RELEASE, __HIP_MEMORY_SCOPE_WORKGROUP);
    } else {
      while (__hip_atomic_load(&sent, __ATOMIC_ACQUIRE, __HIP_MEMORY_SCOPE_WORKGROUP) < t) {}
    }
    asm volatile("" ::: "memory");   // compiler fence: no h-load hoisting

    // ---- h-part
    if constexpr (RING) {
      const uint4* hA4 = (const uint4*)(hbuf + (size_t)rslot * 131072);
      #pragma unroll
      for (int kc = 0; kc < 32; kc += 2) {
        uint4 h0u = hA4[(kc * 4 + koff8) * 128 + arow];
        uint4 h1u = hA4[((kc + 1) * 4 + koff8) * 128 + arow];
        const int lb0 = kc * 256 + l, lb1 = (kc + 1) * 256 + l;
        xa0 = mfma_(as_bf(h0u), as_bf(ldsW[lb0 + 128]), xa0);
        xa1 = mfma_(as_bf(h0u), as_bf(ldsW[lb0 + 192]), xa1);
        xb0 = mfma_(as_bf(h1u), as_bf(ldsW[lb1 + 128]), xb0);
        xb1 = mfma_(as_bf(h1u), as_bf(ldsW[lb1 + 192]), xb1);
      }
    } else {
      const u64* hA = (const u64*)hbuf + (size_t)rslot * 32768;
      #pragma unroll
      for (int kc = 0; kc < 32; kc += 2) {
        const int hi0 = (kc * 4 + koff8) * 256 + arow * 2;
        const int hi1 = ((kc + 1) * 4 + koff8) * 256 + arow * 2;
        union { u64 q[2]; uint4 p4; } h0u, h1u;
        h0u.q[0] = aload(&hA[hi0]); h0u.q[1] = aload(&hA[hi0 + 1]);
        h1u.q[0] = aload(&hA[hi1]); h1u.q[1] = aload(&hA[hi1 + 1]);
        const int lb0 = kc * 256 + l, lb1 = (kc + 1) * 256 + l;
        xa0 = mfma_(as_bf(h0u.p4), as_bf(ldsW[lb0 + 128]), xa0);
        xa1 = mfma_(as_bf(h0u.p4), as_bf(ldsW[lb0 + 192]), xa1);
        xb0 = mfma_(as_bf(h1u.p4), as_bf(ldsW[lb1 + 128]), xb0);
        xb1 = mfma_(as_bf(h1u.p4), as_bf(ldsW[lb1 + 192]), xb1);
      }
    }
    f32x4 acc0 = xa0 + xb0;
    f32x4 acc1 = xa1 + xb1;

    // ---- pointwise (acc0: i|f, acc1: g|o split at col 8)
    float fo0[4], fo1[4];
    #pragma unroll
    for (int j = 0; j < 4; ++j) {
      fo0[j] = __shfl_xor(acc0[j], 8);
      fo1[j] = __shfl_xor(acc1[j], 8);
    }
    unsigned int bfu0 = 0, bfu1 = 0, bfu2 = 0, bfu3 = 0;
    if (c < 8) {
      float hnv[4];
      #pragma unroll
      for (int j = 0; j < 4; ++j) {
        float iv = sigm(acc0[j]);
        float fv = sigm(fo0[j]);
        float gv = tanh_s(acc1[j]);
        float ov = sigm(fo1[j]);
        float cn = fv * creg[j] + iv * gv;
        float hn = ov * tanh_s(cn);
        creg[j] = cn;
        hnv[j] = hn;
        if (t == Tt - 1) {
          size_t off = (size_t)(crow + j) * Dd + dim;
          __hip_atomic_store(&out_h[off], hn, __ATOMIC_RELAXED, __HIP_MEMORY_SCOPE_AGENT);
          __hip_atomic_store(&out_c[off], cn, __ATOMIC_RELAXED, __HIP_MEMORY_SCOPE_AGENT);
        }
      }
      bfu0 = f2bf(hnv[0]); bfu1 = f2bf(hnv[1]);
      bfu2 = f2bf(hnv[2]); bfu3 = f2bf(hnv[3]);
    }

    // ---- in-wave transpose: lane r<16 gathers row (rowbase+r), dims 0..7
    unsigned int w0 = 0, w1 = 0, w2 = 0, w3 = 0;
    #pragma unroll
    for (int j = 0; j < 4; ++j) {
      unsigned int src = (j == 0) ? bfu0 : (j == 1) ? bfu1 : (j == 2) ? bfu2 : bfu3;
      unsigned int lo0 = __shfl((int)src, shbase + 0);
      unsigned int hi0g = __shfl((int)src, shbase + 1);
      unsigned int lo1 = __shfl((int)src, shbase + 2);
      unsigned int hi1g = __shfl((int)src, shbase + 3);
      unsigned int lo2 = __shfl((int)src, shbase + 4);
      unsigned int hi2g = __shfl((int)src, shbase + 5);
      unsigned int lo3 = __shfl((int)src, shbase + 6);
      unsigned int hi3g = __shfl((int)src, shbase + 7);
      bool mine = ((l & 3) == j);
      if (mine) {
        w0 = lo0 | (hi0g << 16);
        w1 = lo1 | (hi1g << 16);
        w2 = lo2 | (hi2g << 16);
        w3 = lo3 | (hi3g << 16);
      }
    }
    if (l < 16) {
      u32x4 val = {w0, w1, w2, w3};
      unsigned short* hw = hbuf + (size_t)wslot * 131072
                           + (size_t)gs * 1024 + (size_t)(rowbase + l) * 8;
      asm volatile("global_store_dwordx4 %0, %1, off sc0 sc1"
                   :: "v"(hw), "v"(val) : "memory");
    }
    asm volatile("s_waitcnt vmcnt(0)" ::: "memory");  // h globally visible
    if (l == 0)
      __hip_atomic_store(myflag, t + 1, __ATOMIC_RELAXED, __HIP_MEMORY_SCOPE_AGENT);
  }

  // ---------- fc head: yhat[b] = sigmoid(hx[b,:] . fc_w + fc_b)
  if (wg < Bb) {
    // wait for BOTH halves to finish (bh-split barrier doesn't cover this)
    {
      const u64* fa = (const u64*)flags;   // 512 u64 total
      int ok;
      do {
        ok = 1;
        #pragma unroll
        for (int r = 0; r < 8; ++r) {
          u64 v = aload(&fa[l + r * 64]);
          ok &= ((int)v >= Tt) && ((int)(v >> 32) >= Tt);
        }
      } while (!__all(ok));
    }
    const u64* hr = (const u64*)(out_h + (size_t)wg * Dd);
    float s = 0.f;
    for (int k = tid; k < Dd / 2; k += NTHR) {
      u64 v = aload(&hr[k]);
      union { u64 u; float f[2]; } q; q.u = v;
      s += q.f[0] * fc_w[2 * k] + q.f[1] * fc_w[2 * k + 1];
    }
    #pragma unroll
    for (int off = 32; off > 0; off >>= 1) s += __shfl_down(s, off);
    if (l == 0) red[w] = s;
    __syncthreads();
    if (tid == 0) {
      float tot = red[0] + red[1] + red[2] + red[3] + fc_b[0];
      out_y[wg] = sigm(tot);
    }
  }
}

extern "C" void kernel_launch(void* const* d_in, const int* in_sizes, int n_in,
                              void* d_out, int out_size, void* d_ws, size_t ws_size,
                              hipStream_t stream) {
  (void)in_sizes; (void)n_in; (void)out_size;
  const float* inp  = (const float*)d_in[0];
  const float* h0   = (const float*)d_in[1];
  const float* c0   = (const float*)d_in[2];
  const float* W_ih = (const float*)d_in[3];
  const float* W_hh = (const float*)d_in[4];
  const float* b_ih = (const float*)d_in[5];
  const float* b_hh = (const float*)d_in[6];
  const float* fc_w = (const float*)d_in[7];
  const float* fc_b = (const float*)d_in[8];
  float* out = (float*)d_out;

  // ws layout: flags 16KB (4 KB used) | hbuf ring | xbf 64MB
  const size_t fbytes = 16384;
  const size_t slot   = (size_t)Bb * Dd * 2;           // 256 KB
  const size_t ring1  = (size_t)(Tt + 1) * slot;       // 67.4 MB
  const size_t ring0  = 2 * slot;                      // 512 KB
  const size_t xbytes = (size_t)Tt * Bb * Dd * 2;      // 64 MB

  int ring, use_xbf;
  size_t rbytes;
  if (ws_size >= fbytes + ring1 + xbytes)      { ring = 1; use_xbf = 1; rbytes = ring1; }
  else if (ws_size >= fbytes + ring1)          { ring = 1; use_xbf = 0; rbytes = ring1; }
  else if (ws_size >= fbytes + ring0 + xbytes) { ring = 0; use_xbf = 1; rbytes = ring0; }
  else                                         { ring = 0; use_xbf = 0; rbytes = ring0; }

  int* flags = (int*)d_ws;
  unsigned short* hbuf = (unsigned short*)((char*)d_ws + fbytes);
  unsigned short* xbf  = (unsigned short*)((char*)d_ws + fbytes + rbytes);

  void* kfn = ring ? (void*)lstm_kernel<1> : (void*)lstm_kernel<0>;
  (void)hipFuncSetAttribute((const void*)kfn,
                            hipFuncAttributeMaxDynamicSharedMemorySize, 131072);

  void* kargs[] = {(void*)&inp, (void*)&h0, (void*)&c0, (void*)&W_ih, (void*)&W_hh,
                   (void*)&b_ih, (void*)&b_hh, (void*)&fc_w, (void*)&fc_b,
                   (void*)&out, (void*)&flags, (void*)&hbuf, (void*)&xbf, (void*)&use_xbf};
  (void)hipLaunchCooperativeKernel(kfn, dim3(NWG), dim3(NTHR),
                                   kargs, 131072u, stream);
}